// Round 1
// baseline (734.349 us; speedup 1.0000x reference)
//
#include <hip/hip_runtime.h>
#include <hip/hip_bf16.h>

// TreeCNN: B=256 trees, layers 2048->256->32->1 (arities 8,8,32), D_IN=128, HID=256, OUT=10.
// All segment indices are contiguous-block structure; implemented as dense group sums.
// Key identity: per-tree sum of h_k == per-tree sum of pooled_{k+1}, so h1/h2 are never
// materialized; only pre-BN Z matrices + pooled tensors + tiny tree-sums live in ws.

#define N0 (256*2048)
#define N1 (256*256)
#define N2 (256*32)
#define NB 256
#define DIN 128
#define HID 256
#define BN_EPS 1e-5f

// ---------------- group-sum of 8 rows of width 128 (x -> pooled1) ----------------
__global__ __launch_bounds__(256) void pool8_128(const float* __restrict__ x,
                                                 float* __restrict__ out) {
    int idx = blockIdx.x * 256 + threadIdx.x;      // N1*128 total
    int d = idx & 127, p = idx >> 7;
    const float* xp = x + (size_t)p * 8 * 128 + d;
    float s = 0.f;
#pragma unroll
    for (int c = 0; c < 8; ++c) s += xp[c * 128];
    out[idx] = s;
}

// ---------------- per-tree sums ----------------
template <int ROWS, int D>
__global__ void treesum(const float* __restrict__ in, float* __restrict__ out) {
    int t = blockIdx.x, d = threadIdx.x;           // blockDim = D
    const float* p = in + (size_t)t * ROWS * D + d;
    float s = 0.f;
    for (int r = 0; r < ROWS; ++r) s += p[(size_t)r * D];
    out[t * D + d] = s;
}

// ---------------- pooled = group-sum of relu(scale*Z+shift), width 256 ----------------
template <int GROUP>
__global__ __launch_bounds__(256) void pool_bn_relu(const float* __restrict__ Z,
                                                    const float* __restrict__ scale,
                                                    const float* __restrict__ shift,
                                                    float* __restrict__ out) {
    int idx = blockIdx.x * 256 + threadIdx.x;      // Nout*256 total
    int d = idx & 255, p = idx >> 8;
    float sc = scale[d], sh = shift[d];
    const float* zp = Z + (size_t)p * GROUP * 256 + d;
    float s = 0.f;
#pragma unroll
    for (int c = 0; c < GROUP; ++c) {
        float v = sc * zp[(size_t)c * 256] + sh;
        s += v > 0.f ? v : 0.f;
    }
    out[idx] = s;
}

// ---------------- column sum / sumsq (BN stats), N=256 cols ----------------
__global__ __launch_bounds__(256) void colstats(const float* __restrict__ Z, int rows_per_block,
                                                float* __restrict__ sum, float* __restrict__ sumsq) {
    int col = threadIdx.x;
    size_t r0 = (size_t)blockIdx.x * rows_per_block;
    float s = 0.f, s2 = 0.f;
    for (int r = 0; r < rows_per_block; ++r) {
        float v = Z[(r0 + r) * 256 + col];
        s += v; s2 += v * v;
    }
    atomicAdd(&sum[col], s);
    atomicAdd(&sumsq[col], s2);
}

__global__ void bn_finalize(const float* __restrict__ sum, const float* __restrict__ sumsq,
                            const float* __restrict__ g, const float* __restrict__ b,
                            float invM, float* __restrict__ scale, float* __restrict__ shift) {
    int d = threadIdx.x;  // 256
    float mean = sum[d] * invM;
    float var = sumsq[d] * invM - mean * mean;
    float s = g[d] * rsqrtf(var + BN_EPS);
    scale[d] = s;
    shift[d] = b[d] - mean * s;
}

// ---------------- tiled f32 GEMM: C[M,256] = f(A[M,K]) @ W[K,256] + bias ----------------
// f = identity, or relu(scale[k]*a+shift[k]) when BN_A (fused BN+ReLU of previous layer).
template <int K_DIM, bool BN_A>
__global__ __launch_bounds__(256) void gemm_kernel(const float* __restrict__ A,
                                                   const float* __restrict__ scale,
                                                   const float* __restrict__ shift,
                                                   const float* __restrict__ W,
                                                   const float* __restrict__ bias,
                                                   float* __restrict__ C, int M) {
    constexpr int BM = 64, BN = 64, BK = 32;
    __shared__ float As[BK][BM + 4];   // +4 pad: 16B-aligned rows for b128 reads
    __shared__ float Bs[BK][BN + 4];
    int m0 = blockIdx.x * BM, n0 = blockIdx.y * BN;
    int tid = threadIdx.x;
    int tx = tid & 15, ty = tid >> 4;
    float acc[4][4] = {};
    for (int k0 = 0; k0 < K_DIM; k0 += BK) {
#pragma unroll
        for (int i = 0; i < 8; ++i) {
            int e = tid + i * 256;
            int m = e >> 5, k = e & 31;
            float v = A[(size_t)(m0 + m) * K_DIM + k0 + k];
            if (BN_A) {
                v = v * scale[k0 + k] + shift[k0 + k];
                v = v > 0.f ? v : 0.f;
            }
            As[k][m] = v;
        }
#pragma unroll
        for (int i = 0; i < 8; ++i) {
            int e = tid + i * 256;
            int k = e >> 6, n = e & 63;
            Bs[k][n] = W[(size_t)(k0 + k) * 256 + n0 + n];
        }
        __syncthreads();
#pragma unroll
        for (int k = 0; k < BK; ++k) {
            float a[4], b[4];
#pragma unroll
            for (int i = 0; i < 4; ++i) a[i] = As[k][ty * 4 + i];
#pragma unroll
            for (int j = 0; j < 4; ++j) b[j] = Bs[k][tx * 4 + j];
#pragma unroll
            for (int i = 0; i < 4; ++i)
#pragma unroll
                for (int j = 0; j < 4; ++j) acc[i][j] += a[i] * b[j];
        }
        __syncthreads();
    }
#pragma unroll
    for (int i = 0; i < 4; ++i) {
        size_t m = m0 + ty * 4 + i;
#pragma unroll
        for (int j = 0; j < 4; ++j) {
            int n = n0 + tx * 4 + j;
            C[m * 256 + n] = acc[i][j] + bias[n];
        }
    }
}

// ---------------- readout heads ----------------
__global__ __launch_bounds__(256) void head_kernel(const float* __restrict__ ts0,
                                                   const float* __restrict__ ts1,
                                                   const float* __restrict__ p3,
                                                   const float* __restrict__ Z3b,
                                                   const float* __restrict__ sc3,
                                                   const float* __restrict__ sh3,
                                                   const float* __restrict__ p0w,
                                                   const float* __restrict__ p0b,
                                                   const float* __restrict__ phw,
                                                   const float* __restrict__ phb,
                                                   float* __restrict__ out) {
    int t = blockIdx.x, d = threadIdx.x;  // 256 threads
    float acc[10];
#pragma unroll
    for (int o = 0; o < 10; ++o) acc[o] = 0.f;
    if (d < 128) {
        float v = ts0[t * 128 + d];
#pragma unroll
        for (int o = 0; o < 10; ++o) acc[o] += v * p0w[d * 10 + o];
    }
    {
        float v = ts1[t * 256 + d];
#pragma unroll
        for (int o = 0; o < 10; ++o) acc[o] += v * phw[d * 10 + o];
    }
    {
        float v = p3[t * 256 + d];
#pragma unroll
        for (int o = 0; o < 10; ++o) acc[o] += v * phw[2560 + d * 10 + o];
    }
    {
        float v = sc3[d] * Z3b[t * 256 + d] + sh3[d];
        v = v > 0.f ? v : 0.f;
#pragma unroll
        for (int o = 0; o < 10; ++o) acc[o] += v * phw[5120 + d * 10 + o];
    }
    __shared__ float red[256];
    for (int o = 0; o < 10; ++o) {
        red[d] = acc[o];
        __syncthreads();
        for (int s = 128; s > 0; s >>= 1) {
            if (d < s) red[d] += red[d + s];
            __syncthreads();
        }
        if (d == 0) out[t * 10 + o] = red[0] + p0b[o] + phb[o] + phb[10 + o] + phb[20 + o];
        __syncthreads();
    }
}

extern "C" void kernel_launch(void* const* d_in, const int* in_sizes, int n_in,
                              void* d_out, int out_size, void* d_ws, size_t ws_size,
                              hipStream_t stream) {
    const float* x       = (const float*)d_in[0];
    const float* l1_w1   = (const float*)d_in[7];
    const float* l1_b1   = (const float*)d_in[8];
    const float* l1_bn1g = (const float*)d_in[9];
    const float* l1_bn1b = (const float*)d_in[10];
    const float* l1_w2   = (const float*)d_in[11];
    const float* l1_b2   = (const float*)d_in[12];
    const float* l1_bng  = (const float*)d_in[13];
    const float* l1_bnb  = (const float*)d_in[14];
    const float* lw1     = (const float*)d_in[15];
    const float* lb1     = (const float*)d_in[16];
    const float* lbn1g   = (const float*)d_in[17];
    const float* lbn1b   = (const float*)d_in[18];
    const float* lw2     = (const float*)d_in[19];
    const float* lb2     = (const float*)d_in[20];
    const float* lbng    = (const float*)d_in[21];
    const float* lbnb    = (const float*)d_in[22];
    const float* pred0_w = (const float*)d_in[23];
    const float* pred0_b = (const float*)d_in[24];
    const float* predh_w = (const float*)d_in[25];
    const float* predh_b = (const float*)d_in[26];
    float* out = (float*)d_out;

    float* ws = (float*)d_ws;
    // region0: Z1 [65536,256]; after GEMM1b it is reused for layer-2/3 smalls
    float* Z1 = ws;                                   // 16,777,216 floats
    // region1: pooled1 [65536,128] first, then Z2 [65536,256] (pooled1 dead by then)
    float* pooled1 = ws + 16777216;
    float* Z2 = ws + 16777216;                        // 16,777,216 floats
    // tail: tree sums + stats
    float* tail = ws + 2 * 16777216;
    float* ts0 = tail;                                // 256*128
    float* ts1 = tail + 32768;                        // 256*256
    float* stats = tail + 32768 + 65536;              // 6*1024 floats
    // smalls aliased into Z1 region (Z1 dead after GEMM1b):
    float* pooled2 = Z1;                              // 8192*256
    float* Z2a     = Z1 + 2097152;                    // 8192*256
    float* Z2b     = Z1 + 2 * 2097152;                // 8192*256
    float* pooled3 = Z1 + 3 * 2097152;                // 256*256
    float* Z3a     = pooled3 + 65536;                 // 256*256
    float* Z3b     = Z3a + 65536;                     // 256*256

    // stats slot i: sum=+0, sumsq=+256, scale=+512, shift=+768
    auto S = [&](int i) { return stats + i * 1024; };
    // 0: L1 inner BN (Z1), 1: L1 outer BN (Z2), 2: L2 inner (Z2a), 3: L2 outer (Z2b),
    // 4: L3 inner (Z3a), 5: L3 outer (Z3b)
    hipMemsetAsync(stats, 0, 6 * 1024 * sizeof(float), stream);

    // layer 1
    pool8_128<<<N1 * 128 / 256, 256, 0, stream>>>(x, pooled1);
    treesum<256, 128><<<NB, 128, 0, stream>>>(pooled1, ts0);
    gemm_kernel<128, false><<<dim3(N1 / 64, 4), 256, 0, stream>>>(
        pooled1, nullptr, nullptr, l1_w1, l1_b1, Z1, N1);
    colstats<<<N1 / 256, 256, 0, stream>>>(Z1, 256, S(0), S(0) + 256);
    bn_finalize<<<1, 256, 0, stream>>>(S(0), S(0) + 256, l1_bn1g, l1_bn1b,
                                       1.f / N1, S(0) + 512, S(0) + 768);
    gemm_kernel<256, true><<<dim3(N1 / 64, 4), 256, 0, stream>>>(
        Z1, S(0) + 512, S(0) + 768, l1_w2, l1_b2, Z2, N1);
    colstats<<<N1 / 256, 256, 0, stream>>>(Z2, 256, S(1), S(1) + 256);
    bn_finalize<<<1, 256, 0, stream>>>(S(1), S(1) + 256, l1_bng, l1_bnb,
                                       1.f / N1, S(1) + 512, S(1) + 768);
    // pooled2 = group8 of h1 = relu(bn(Z2));  ts1 = per-tree sums of pooled2
    pool_bn_relu<8><<<N2 * 256 / 256, 256, 0, stream>>>(Z2, S(1) + 512, S(1) + 768, pooled2);
    treesum<32, 256><<<NB, 256, 0, stream>>>(pooled2, ts1);

    // layer 2
    gemm_kernel<256, false><<<dim3(N2 / 64, 4), 256, 0, stream>>>(
        pooled2, nullptr, nullptr, lw1, lb1, Z2a, N2);
    colstats<<<N2 / 256, 256, 0, stream>>>(Z2a, 256, S(2), S(2) + 256);
    bn_finalize<<<1, 256, 0, stream>>>(S(2), S(2) + 256, lbn1g, lbn1b,
                                       1.f / N2, S(2) + 512, S(2) + 768);
    gemm_kernel<256, true><<<dim3(N2 / 64, 4), 256, 0, stream>>>(
        Z2a, S(2) + 512, S(2) + 768, lw2, lb2, Z2b, N2);
    colstats<<<N2 / 256, 256, 0, stream>>>(Z2b, 256, S(3), S(3) + 256);
    bn_finalize<<<1, 256, 0, stream>>>(S(3), S(3) + 256, lbng, lbnb,
                                       1.f / N2, S(3) + 512, S(3) + 768);
    // pooled3 = group32 of h2  (== per-tree sum of h2, since 32 nodes/tree at layer 2)
    pool_bn_relu<32><<<NB * 256 / 256, 256, 0, stream>>>(Z2b, S(3) + 512, S(3) + 768, pooled3);

    // layer 3 (weights at index 1 of stacked arrays)
    gemm_kernel<256, false><<<dim3(NB / 64, 4), 256, 0, stream>>>(
        pooled3, nullptr, nullptr, lw1 + 65536, lb1 + 256, Z3a, NB);
    colstats<<<1, 256, 0, stream>>>(Z3a, 256, S(4), S(4) + 256);
    bn_finalize<<<1, 256, 0, stream>>>(S(4), S(4) + 256, lbn1g + 256, lbn1b + 256,
                                       1.f / NB, S(4) + 512, S(4) + 768);
    gemm_kernel<256, true><<<dim3(NB / 64, 4), 256, 0, stream>>>(
        Z3a, S(4) + 512, S(4) + 768, lw2 + 65536, lb2 + 256, Z3b, NB);
    colstats<<<1, 256, 0, stream>>>(Z3b, 256, S(5), S(5) + 256);
    bn_finalize<<<1, 256, 0, stream>>>(S(5), S(5) + 256, lbng + 256, lbnb + 256,
                                       1.f / NB, S(5) + 512, S(5) + 768);

    // readout
    head_kernel<<<NB, 256, 0, stream>>>(ts0, ts1, pooled3, Z3b, S(5) + 512, S(5) + 768,
                                        pred0_w, pred0_b, predh_w, predh_b, out);
}

// Round 2
// 190.268 us; speedup vs baseline: 3.8596x; 3.8596x over previous
//
#include <hip/hip_runtime.h>
#include <hip/hip_bf16.h>

// TreeCNN on MI355X — bf16 MFMA version.
// B=256 trees, 2048->256->32->1 (arities 8,8,32), D_IN=128, HID=256, OUT=10.
// Segment indices are contiguous-block structure -> dense group sums.
// h1/h2 never materialized: only pre-BN Z (bf16) + pooled tensors (bf16) + tree-sums.
// BN stats fused into GEMM epilogue (32-slot atomic partials); BN+ReLU applied on
// the next consumer's A-load.

#define N0 (256*2048)
#define N1 (256*256)
#define N2 (256*32)
#define NB 256
#define BN_EPS 1e-5f

typedef __attribute__((ext_vector_type(8))) __bf16 bf16x8;
typedef __attribute__((ext_vector_type(8))) unsigned short u16x8;
typedef __attribute__((ext_vector_type(4))) unsigned short u16x4;
typedef __attribute__((ext_vector_type(4))) float f32x4;

__device__ inline float bf2f(unsigned short b) {
    unsigned u = ((unsigned)b) << 16;
    float f; __builtin_memcpy(&f, &u, 4); return f;
}
__device__ inline unsigned short f2bf(float f) {
    unsigned u; __builtin_memcpy(&u, &f, 4);
    u += 0x7fff + ((u >> 16) & 1);
    return (unsigned short)(u >> 16);
}

// ---------- weights: transpose + f32->bf16, Wt[n][k] ----------
__global__ __launch_bounds__(256) void prep_weights(const float* __restrict__ l1_w1,
                                                    const float* __restrict__ l1_w2,
                                                    const float* __restrict__ lw1,
                                                    const float* __restrict__ lw2,
                                                    unsigned short* __restrict__ Wt) {
    int idx = blockIdx.x * 256 + threadIdx.x;
    if (idx >= 360448) return;
    float v;
    if (idx < 32768) {                       // l1_w1 [128,256] -> [256][128]
        int n = idx >> 7, k = idx & 127;
        v = l1_w1[k * 256 + n];
    } else if (idx < 98304) {                // l1_w2 [256,256]
        int j = idx - 32768, n = j >> 8, k = j & 255;
        v = l1_w2[k * 256 + n];
    } else if (idx < 163840) {               // lw1[0]
        int j = idx - 98304, n = j >> 8, k = j & 255;
        v = lw1[k * 256 + n];
    } else if (idx < 229376) {               // lw2[0]
        int j = idx - 163840, n = j >> 8, k = j & 255;
        v = lw2[k * 256 + n];
    } else if (idx < 294912) {               // lw1[1]
        int j = idx - 229376, n = j >> 8, k = j & 255;
        v = lw1[65536 + k * 256 + n];
    } else {                                 // lw2[1]
        int j = idx - 294912, n = j >> 8, k = j & 255;
        v = lw2[65536 + k * 256 + n];
    }
    Wt[idx] = f2bf(v);
}

// ---------- x (f32) -> pooled1 (bf16), group-8 sum, width 128 ----------
__global__ __launch_bounds__(256) void pool8_128(const float* __restrict__ x,
                                                 unsigned short* __restrict__ out) {
    int v = blockIdx.x * 256 + threadIdx.x;   // N1*32 vectors of 4
    int c4 = v & 31, p = v >> 5;
    const f32x4* xp = reinterpret_cast<const f32x4*>(x + (size_t)p * 8 * 128 + c4 * 4);
    f32x4 s = {0.f, 0.f, 0.f, 0.f};
#pragma unroll
    for (int c = 0; c < 8; ++c) s += xp[c * 32];
    u16x4 o;
#pragma unroll
    for (int e = 0; e < 4; ++e) o[e] = f2bf(s[e]);
    *reinterpret_cast<u16x4*>(out + (size_t)p * 128 + c4 * 4) = o;
}

// ---------- per-tree sums (bf16 in, f32 out) ----------
template <int ROWS, int D>
__global__ void treesum_bf(const unsigned short* __restrict__ in, float* __restrict__ out) {
    int t = blockIdx.x, d = threadIdx.x;     // blockDim = D
    const unsigned short* p = in + (size_t)t * ROWS * D + d;
    float s = 0.f;
    for (int r = 0; r < ROWS; ++r) s += bf2f(p[(size_t)r * D]);
    out[t * D + d] = s;
}

// ---------- pooled = group-sum of relu(scale*Z+shift), bf16 io, width 256 ----------
template <int GROUP>
__global__ __launch_bounds__(256) void pool_bn_relu(const unsigned short* __restrict__ Z,
                                                    const float* __restrict__ scale,
                                                    const float* __restrict__ shift,
                                                    unsigned short* __restrict__ out) {
    int v = blockIdx.x * 256 + threadIdx.x;  // Nout*32 vectors of 8
    int c8 = v & 31, p = v >> 5;
    int d0 = c8 * 8;
    float sc[8], sh[8], s[8];
#pragma unroll
    for (int e = 0; e < 8; ++e) { sc[e] = scale[d0 + e]; sh[e] = shift[d0 + e]; s[e] = 0.f; }
#pragma unroll
    for (int g = 0; g < GROUP; ++g) {
        u16x8 z = *reinterpret_cast<const u16x8*>(Z + ((size_t)p * GROUP + g) * 256 + d0);
#pragma unroll
        for (int e = 0; e < 8; ++e) {
            float f = sc[e] * bf2f(z[e]) + sh[e];
            s[e] += f > 0.f ? f : 0.f;
        }
    }
    u16x8 o;
#pragma unroll
    for (int e = 0; e < 8; ++e) o[e] = f2bf(s[e]);
    *reinterpret_cast<u16x8*>(out + (size_t)p * 256 + d0) = o;
}

// ---------- BN finalize: reduce 32 partial slots -> scale/shift ----------
__global__ void bn_finalize(const float* __restrict__ partials,  // [32][512]
                            const float* __restrict__ g, const float* __restrict__ b,
                            float invM, float* __restrict__ ss /* scale[256],shift[256] */) {
    int d = threadIdx.x;  // 256
    float s = 0.f, s2 = 0.f;
    for (int slot = 0; slot < 32; ++slot) {
        s  += partials[slot * 512 + d];
        s2 += partials[slot * 512 + 256 + d];
    }
    float mean = s * invM;
    float var = s2 * invM - mean * mean;
    float sc = g[d] * rsqrtf(var + BN_EPS);
    ss[d] = sc;
    ss[256 + d] = b[d] - mean * sc;
}

// ---------- MFMA GEMM: C[M,256](bf16) = f(A[M,K]) @ Wt^T + bias; col-stats fused ----------
// f = identity or relu(scale[k]*a+shift[k]) (BN+ReLU of previous layer, on A-load).
// Block: 64 rows x 256 cols, 4 waves each own 64x64. Wt is [256][K] bf16 (n-major).
template <int KD, bool BN_A>
__global__ __launch_bounds__(256) void mfma_gemm(const unsigned short* __restrict__ A,
                                                 const float* __restrict__ scale,
                                                 const float* __restrict__ shift,
                                                 const unsigned short* __restrict__ Wt,
                                                 const float* __restrict__ bias,
                                                 unsigned short* __restrict__ C,
                                                 float* __restrict__ stat_partials) {
    constexpr int LDA = 72;  // padded bf16 row stride (144 B -> even bank spread)
    __shared__ unsigned short Asb[64 * LDA];
    __shared__ unsigned short Bsb[256 * LDA];
    const int m0 = blockIdx.x * 64;
    const int tid = threadIdx.x;
    const int wave = tid >> 6, lane = tid & 63;
    const int q = lane >> 4, r = lane & 15;

    f32x4 acc[4][4];
#pragma unroll
    for (int i = 0; i < 4; ++i)
#pragma unroll
        for (int j = 0; j < 4; ++j) acc[i][j] = (f32x4){0.f, 0.f, 0.f, 0.f};

    for (int k0 = 0; k0 < KD; k0 += 64) {
        // stage A tile: 64 rows x 64 k
#pragma unroll
        for (int i = 0; i < 2; ++i) {
            int v = tid + i * 256;           // 0..511
            int row = v >> 3, kc = v & 7;
            u16x8 d = *reinterpret_cast<const u16x8*>(A + (size_t)(m0 + row) * KD + k0 + kc * 8);
            if (BN_A) {
                u16x8 o;
#pragma unroll
                for (int e = 0; e < 8; ++e) {
                    int k = k0 + kc * 8 + e;
                    float f = scale[k] * bf2f(d[e]) + shift[k];
                    o[e] = f2bf(f > 0.f ? f : 0.f);
                }
                d = o;
            }
            *reinterpret_cast<u16x8*>(&Asb[row * LDA + kc * 8]) = d;
        }
        // stage B tile: 256 n x 64 k (from n-major Wt)
#pragma unroll
        for (int i = 0; i < 8; ++i) {
            int v = tid + i * 256;           // 0..2047
            int n = v >> 3, kc = v & 7;
            u16x8 d = *reinterpret_cast<const u16x8*>(Wt + (size_t)n * KD + k0 + kc * 8);
            *reinterpret_cast<u16x8*>(&Bsb[n * LDA + kc * 8]) = d;
        }
        __syncthreads();
#pragma unroll
        for (int s = 0; s < 2; ++s) {        // two k-steps of 32
            bf16x8 a[4], b[4];
#pragma unroll
            for (int i = 0; i < 4; ++i)
                a[i] = *reinterpret_cast<const bf16x8*>(&Asb[(i * 16 + r) * LDA + s * 32 + q * 8]);
#pragma unroll
            for (int j = 0; j < 4; ++j)
                b[j] = *reinterpret_cast<const bf16x8*>(&Bsb[(wave * 64 + j * 16 + r) * LDA + s * 32 + q * 8]);
#pragma unroll
            for (int i = 0; i < 4; ++i)
#pragma unroll
                for (int j = 0; j < 4; ++j)
                    acc[i][j] = __builtin_amdgcn_mfma_f32_16x16x32_bf16(a[i], b[j], acc[i][j], 0, 0, 0);
        }
        __syncthreads();
    }

    // epilogue: +bias, column stats, bf16 store.
    // C/D layout: col = r (lane&15), row = q*4 + e.
    const int col_base = wave * 64;
    float sj[4], s2j[4];
#pragma unroll
    for (int j = 0; j < 4; ++j) {
        float bj = bias[col_base + j * 16 + r];
        float s = 0.f, s2 = 0.f;
#pragma unroll
        for (int i = 0; i < 4; ++i)
#pragma unroll
            for (int e = 0; e < 4; ++e) {
                acc[i][j][e] += bj;
                float v = acc[i][j][e];
                s += v; s2 += v * v;
            }
        s  += __shfl_xor(s, 16);  s  += __shfl_xor(s, 32);
        s2 += __shfl_xor(s2, 16); s2 += __shfl_xor(s2, 32);
        sj[j] = s; s2j[j] = s2;
    }
#pragma unroll
    for (int i = 0; i < 4; ++i)
#pragma unroll
        for (int e = 0; e < 4; ++e) {
            size_t row = m0 + i * 16 + q * 4 + e;
#pragma unroll
            for (int j = 0; j < 4; ++j)
                C[row * 256 + col_base + j * 16 + r] = f2bf(acc[i][j][e]);
        }
    if (q == 0) {
        int slot = blockIdx.x & 31;
#pragma unroll
        for (int j = 0; j < 4; ++j) {
            int col = col_base + j * 16 + r;
            atomicAdd(&stat_partials[slot * 512 + col], sj[j]);
            atomicAdd(&stat_partials[slot * 512 + 256 + col], s2j[j]);
        }
    }
}

// ---------- readout heads ----------
__global__ __launch_bounds__(256) void head_kernel(const float* __restrict__ ts0,
                                                   const float* __restrict__ ts1,
                                                   const unsigned short* __restrict__ p3,
                                                   const unsigned short* __restrict__ Z3b,
                                                   const float* __restrict__ ss5,
                                                   const float* __restrict__ p0w,
                                                   const float* __restrict__ p0b,
                                                   const float* __restrict__ phw,
                                                   const float* __restrict__ phb,
                                                   float* __restrict__ out) {
    int t = blockIdx.x, d = threadIdx.x;  // 256 threads
    float acc[10];
#pragma unroll
    for (int o = 0; o < 10; ++o) acc[o] = 0.f;
    if (d < 128) {
        float v = ts0[t * 128 + d];
#pragma unroll
        for (int o = 0; o < 10; ++o) acc[o] += v * p0w[d * 10 + o];
    }
    {
        float v = ts1[t * 256 + d];
#pragma unroll
        for (int o = 0; o < 10; ++o) acc[o] += v * phw[d * 10 + o];
    }
    {
        float v = bf2f(p3[t * 256 + d]);
#pragma unroll
        for (int o = 0; o < 10; ++o) acc[o] += v * phw[2560 + d * 10 + o];
    }
    {
        float v = ss5[d] * bf2f(Z3b[t * 256 + d]) + ss5[256 + d];
        v = v > 0.f ? v : 0.f;
#pragma unroll
        for (int o = 0; o < 10; ++o) acc[o] += v * phw[5120 + d * 10 + o];
    }
    __shared__ float red[256];
    for (int o = 0; o < 10; ++o) {
        red[d] = acc[o];
        __syncthreads();
        for (int s = 128; s > 0; s >>= 1) {
            if (d < s) red[d] += red[d + s];
            __syncthreads();
        }
        if (d == 0) out[t * 10 + o] = red[0] + p0b[o] + phb[o] + phb[10 + o] + phb[20 + o];
        __syncthreads();
    }
}

extern "C" void kernel_launch(void* const* d_in, const int* in_sizes, int n_in,
                              void* d_out, int out_size, void* d_ws, size_t ws_size,
                              hipStream_t stream) {
    const float* x       = (const float*)d_in[0];
    const float* l1_w1   = (const float*)d_in[7];
    const float* l1_b1   = (const float*)d_in[8];
    const float* l1_bn1g = (const float*)d_in[9];
    const float* l1_bn1b = (const float*)d_in[10];
    const float* l1_w2   = (const float*)d_in[11];
    const float* l1_b2   = (const float*)d_in[12];
    const float* l1_bng  = (const float*)d_in[13];
    const float* l1_bnb  = (const float*)d_in[14];
    const float* lw1     = (const float*)d_in[15];
    const float* lb1     = (const float*)d_in[16];
    const float* lbn1g   = (const float*)d_in[17];
    const float* lbn1b   = (const float*)d_in[18];
    const float* lw2     = (const float*)d_in[19];
    const float* lb2     = (const float*)d_in[20];
    const float* lbng    = (const float*)d_in[21];
    const float* lbnb    = (const float*)d_in[22];
    const float* pred0_w = (const float*)d_in[23];
    const float* pred0_b = (const float*)d_in[24];
    const float* predh_w = (const float*)d_in[25];
    const float* predh_b = (const float*)d_in[26];
    float* out = (float*)d_out;

    uint8_t* wsb = (uint8_t*)d_ws;
    unsigned short* pooled1 = (unsigned short*)(wsb);                          // 16 MB
    unsigned short* Z1      = (unsigned short*)(wsb + (16ull << 20));          // 32 MB
    unsigned short* Z2      = (unsigned short*)(wsb + (48ull << 20));          // 32 MB
    unsigned short* pooled2 = (unsigned short*)(wsb + (80ull << 20));          // 4 MB
    unsigned short* Z2a     = (unsigned short*)(wsb + (84ull << 20));          // 4 MB
    unsigned short* Z2b     = (unsigned short*)(wsb + (88ull << 20));          // 4 MB
    unsigned short* pooled3 = (unsigned short*)(wsb + (92ull << 20));          // 128 KB
    unsigned short* Z3a     = (unsigned short*)(wsb + (92ull << 20) + 131072); // 128 KB
    unsigned short* Z3b     = (unsigned short*)(wsb + (92ull << 20) + 262144); // 128 KB
    unsigned short* Wt      = (unsigned short*)(wsb + (93ull << 20));          // 720 KB
    float* ts0   = (float*)(wsb + (94ull << 20));                              // 128 KB
    float* ts1   = (float*)(wsb + (94ull << 20) + 131072);                     // 256 KB
    float* stats = (float*)(wsb + (95ull << 20));  // 6x [32][512] partials + 6x[512] ss

    auto SP = [&](int i) { return stats + i * 16384; };
    float* ssbase = stats + 6 * 16384;
    auto SS = [&](int i) { return ssbase + i * 512; };

    hipMemsetAsync(stats, 0, 6 * 16384 * sizeof(float), stream);
    prep_weights<<<1408, 256, 0, stream>>>(l1_w1, l1_w2, lw1, lw2, Wt);

    // layer 1
    pool8_128<<<N1 * 32 / 256, 256, 0, stream>>>(x, pooled1);
    treesum_bf<256, 128><<<NB, 128, 0, stream>>>(pooled1, ts0);
    mfma_gemm<128, false><<<N1 / 64, 256, 0, stream>>>(pooled1, nullptr, nullptr,
                                                       Wt, l1_b1, Z1, SP(0));
    bn_finalize<<<1, 256, 0, stream>>>(SP(0), l1_bn1g, l1_bn1b, 1.f / N1, SS(0));
    mfma_gemm<256, true><<<N1 / 64, 256, 0, stream>>>(Z1, SS(0), SS(0) + 256,
                                                      Wt + 32768, l1_b2, Z2, SP(1));
    bn_finalize<<<1, 256, 0, stream>>>(SP(1), l1_bng, l1_bnb, 1.f / N1, SS(1));
    pool_bn_relu<8><<<N2 * 32 / 256, 256, 0, stream>>>(Z2, SS(1), SS(1) + 256, pooled2);
    treesum_bf<32, 256><<<NB, 256, 0, stream>>>(pooled2, ts1);

    // layer 2
    mfma_gemm<256, false><<<N2 / 64, 256, 0, stream>>>(pooled2, nullptr, nullptr,
                                                       Wt + 98304, lb1, Z2a, SP(2));
    bn_finalize<<<1, 256, 0, stream>>>(SP(2), lbn1g, lbn1b, 1.f / N2, SS(2));
    mfma_gemm<256, true><<<N2 / 64, 256, 0, stream>>>(Z2a, SS(2), SS(2) + 256,
                                                      Wt + 163840, lb2, Z2b, SP(3));
    bn_finalize<<<1, 256, 0, stream>>>(SP(3), lbng, lbnb, 1.f / N2, SS(3));
    pool_bn_relu<32><<<NB * 32 / 256, 256, 0, stream>>>(Z2b, SS(3), SS(3) + 256, pooled3);

    // layer 3 (weight index 1)
    mfma_gemm<256, false><<<NB / 64, 256, 0, stream>>>(pooled3, nullptr, nullptr,
                                                       Wt + 229376, lb1 + 256, Z3a, SP(4));
    bn_finalize<<<1, 256, 0, stream>>>(SP(4), lbn1g + 256, lbn1b + 256, 1.f / NB, SS(4));
    mfma_gemm<256, true><<<NB / 64, 256, 0, stream>>>(Z3a, SS(4), SS(4) + 256,
                                                      Wt + 294912, lb2 + 256, Z3b, SP(5));
    bn_finalize<<<1, 256, 0, stream>>>(SP(5), lbng + 256, lbnb + 256, 1.f / NB, SS(5));

    // readout
    head_kernel<<<NB, 256, 0, stream>>>(ts0, ts1, pooled3, Z3b, SS(5),
                                        pred0_w, pred0_b, predh_w, predh_b, out);
}